// Round 1
// baseline (198.236 us; speedup 1.0000x reference)
//
#include <hip/hip_runtime.h>

// ============================================================
// Compile-time reproduction of np.random.RandomState(0).randn
// (MT19937 + polar Box-Muller). All control flow / uniforms are
// exact integer & IEEE-double arithmetic -> constexpr-safe.
// Only log/sqrt are evaluated on device (ulp-level differences
// are far below the validation threshold).
// ============================================================
struct MTS { unsigned int mt[624]; int mti; };

constexpr unsigned int mt_next(MTS& s){
  if (s.mti >= 624){
    for (int i = 0; i < 624; i++){
      unsigned int y = (s.mt[i] & 0x80000000u) | (s.mt[(i+1)%624] & 0x7fffffffu);
      unsigned int v = s.mt[(i+397)%624] ^ (y >> 1);
      if (y & 1u) v ^= 2567483615u;   // 0x9908b0df
      s.mt[i] = v;
    }
    s.mti = 0;
  }
  unsigned int y = s.mt[s.mti]; s.mti++;
  y ^= y >> 11;
  y ^= (y << 7)  & 2636928640u;  // 0x9d2c5680
  y ^= (y << 15) & 4022730752u;  // 0xefc60000
  y ^= y >> 18;
  return y;
}
constexpr double mt_dbl(MTS& s){
  unsigned int a = mt_next(s) >> 5;
  unsigned int b = mt_next(s) >> 6;
  return ((double)a * 67108864.0 + (double)b) / 9007199254740992.0;
}

constexpr int NPAIR = 308;   // 615 gaussians -> 308 polar pairs
struct GenData {
  double r2[NPAIR], x1[NPAIR], x2[NPAIR];
  int g_of_t[729];           // T flat index -> gauss index (-1 = structural zero)
};

constexpr GenData make_gen(){
  GenData g{};
  for (int i = 0; i < 729; i++) g.g_of_t[i] = -1;
  MTS s{};
  {
    unsigned int sd = 0u;    // RandomState(0) -> mt19937_seed(0)
    for (int p = 0; p < 624; p++){
      s.mt[p] = sd;
      sd = 1812433253u * (sd ^ (sd >> 30)) + (unsigned)p + 1u;
    }
    s.mti = 624;
  }
  for (int p = 0; p < NPAIR; p++){
    double a = 0.0, b = 0.0, r = 0.0;
    do {
      a = 2.0 * mt_dbl(s) - 1.0;
      b = 2.0 * mt_dbl(s) - 1.0;
      r = a*a + b*b;
    } while (r >= 1.0 || r == 0.0);
    g.r2[p] = r; g.x1[p] = a; g.x2[p] = b;
  }
  // PATHS in module order; OFF = {0,1,4}
  const int L1[15] = {0,0,0,1,1,1,1,1,1,2,2,2,2,2,2};
  const int L2[15] = {0,1,2,0,1,1,1,2,2,0,1,1,2,2,2};
  const int L3[15] = {0,1,2,1,0,1,2,1,2,2,1,2,0,1,2};
  const int OFF[3] = {0,1,4};
  int gi = 0;
  for (int p = 0; p < 15; p++){
    int d1 = 2*L1[p]+1, d2 = 2*L2[p]+1, d3 = 2*L3[p]+1;
    for (int i = 0; i < d1; i++)
      for (int j = 0; j < d2; j++)
        for (int k = 0; k < d3; k++)
          g.g_of_t[(OFF[L1[p]]+i)*81 + (OFF[L2[p]]+j)*9 + (OFF[L3[p]]+k)] = gi++;
  }
  return g;
}

constexpr GenData h_gd = make_gen();
__constant__ GenData c_gd = h_gd;

// Writes the dense 9x9x9 tensor T (615 CG values + zeros) to ws.
__global__ void gen_T_kernel(float* __restrict__ T){
  int t = blockIdx.x * blockDim.x + threadIdx.x;
  if (t >= 729) return;
  int gi = c_gd.g_of_t[t];
  float v = 0.f;
  if (gi >= 0){
    int p = gi >> 1;
    double r2 = c_gd.r2[p];
    double f  = sqrt(-2.0 * log(r2) / r2);
    double xx = (gi & 1) ? c_gd.x1[p] : c_gd.x2[p];  // even idx = f*x2 (returned first), odd = f*x1 (cached)
    v = (float)((f * xx) / 3.0);
  }
  T[t] = v;
}

// ============================================================
// CSR-by-dst construction: hist -> scan -> fill
// ============================================================
__global__ __launch_bounds__(256) void hist_kernel(const int* __restrict__ dst,
                                                   int* __restrict__ cnt,
                                                   int* __restrict__ pos, int E){
  int e = blockIdx.x * 256 + threadIdx.x;
  if (e < E) pos[e] = atomicAdd(&cnt[dst[e]], 1);
}

__global__ void scan_kernel(const int* __restrict__ cnt, int* __restrict__ start, int n){
  __shared__ int part[1024];
  int t = threadIdx.x;
  int ch = (n + 1023) >> 10;
  int b0 = t * ch;
  int sum = 0;
  for (int j = 0; j < ch; j++){ int i = b0 + j; if (i < n) sum += cnt[i]; }
  part[t] = sum;
  __syncthreads();
  for (int off = 1; off < 1024; off <<= 1){
    int v = 0;
    if (t >= off) v = part[t - off];
    __syncthreads();
    part[t] += v;
    __syncthreads();
  }
  int run = (t > 0) ? part[t-1] : 0;
  for (int j = 0; j < ch; j++){
    int i = b0 + j;
    if (i < n){ start[i] = run; run += cnt[i]; }
  }
  if (t == 1023) start[n] = part[1023];
}

__global__ __launch_bounds__(256) void fill_kernel(const int* __restrict__ dst,
                                                   const int* __restrict__ start,
                                                   const int* __restrict__ pos,
                                                   int* __restrict__ csr, int E){
  int e = blockIdx.x * 256 + threadIdx.x;
  if (e < E) csr[start[dst[e]] + pos[e]] = e;
}

// ============================================================
// Main TP kernel: one wave per node, lane = channel (64).
// Per edge: build W[9][9] = sh . T cooperatively in LDS (shared
// across the 64 channels), then per-lane 9x9 matvec, accumulate
// the node's out-row in registers, single store at the end.
// ============================================================
__global__ __launch_bounds__(256) void tp_csr_kernel(
    const float* __restrict__ x, const float* __restrict__ sh,
    const int* __restrict__ src, const int* __restrict__ csr,
    const int* __restrict__ starts, const float* __restrict__ Tg,
    float* __restrict__ out, int n_nodes)
{
  __shared__ float Tl[729];
  __shared__ __align__(16) float Wl[4][112];   // per-wave W tile, rows padded to 12
  for (int i = threadIdx.x; i < 729; i += 256) Tl[i] = Tg[i];
  __syncthreads();

  const int wv = threadIdx.x >> 6;
  const int lane = threadIdx.x & 63;
  const int node = blockIdx.x * 4 + wv;
  if (node >= n_nodes) return;

  float acc[9];
#pragma unroll
  for (int k = 0; k < 9; k++) acc[k] = 0.f;

  const int s0 = starts[node];
  const int s1 = starts[node + 1];

  // W-build entry assignment: entries 0..80 over 64 lanes (2 rounds)
  const int i0 = lane / 9, k0 = lane % 9;
  const bool has1 = (lane < 17);
  const int i1 = (lane + 64) / 9, k1 = (lane + 64) % 9;
  float* Wp = Wl[wv];

  for (int idx = s0; idx < s1; ++idx){
    const int e  = __builtin_amdgcn_readfirstlane(csr[idx]);
    const int sn = __builtin_amdgcn_readfirstlane(src[e]);

    const float* she = sh + (size_t)e * 9;
    float sv[9];
#pragma unroll
    for (int j = 0; j < 9; j++) sv[j] = she[j];

    // ---- cooperative W build: W[i][k] = sum_j sh[j]*T[i][j][k] ----
    float w0 = 0.f;
#pragma unroll
    for (int j = 0; j < 9; j++) w0 += sv[j] * Tl[i0*81 + j*9 + k0];
    Wp[i0*12 + k0] = w0;
    if (has1){
      float w1 = 0.f;
#pragma unroll
      for (int j = 0; j < 9; j++) w1 += sv[j] * Tl[i1*81 + j*9 + k1];
      Wp[i1*12 + k1] = w1;
    }
    // same-wave LDS write->read visibility (LDS is in-order per wave;
    // this drains the writes and fences compiler reordering)
    asm volatile("s_waitcnt lgkmcnt(0)" ::: "memory");

    // ---- per-lane x fragment (channel = lane) ----
    const float* xr = x + (size_t)sn * 576;
    float xv[9];
    xv[0] = xr[lane];
#pragma unroll
    for (int t2 = 0; t2 < 3; t2++) xv[1 + t2] = xr[64 + 3*lane + t2];
#pragma unroll
    for (int t2 = 0; t2 < 5; t2++) xv[4 + t2] = xr[256 + 5*lane + t2];

    // ---- matvec: acc[k] += xv[i] * W[i][k] (broadcast LDS reads) ----
#pragma unroll
    for (int i = 0; i < 9; i++){
      const float4* wr4 = reinterpret_cast<const float4*>(Wp + i*12);
      float4 wa = wr4[0];
      float4 wb = wr4[1];
      float  w8 = Wp[i*12 + 8];
      float xi = xv[i];
      acc[0] += xi * wa.x; acc[1] += xi * wa.y; acc[2] += xi * wa.z; acc[3] += xi * wa.w;
      acc[4] += xi * wb.x; acc[5] += xi * wb.y; acc[6] += xi * wb.z; acc[7] += xi * wb.w;
      acc[8] += xi * w8;
    }
    asm volatile("" ::: "memory");  // keep next iter's W writes after these reads
  }

  float* orow = out + (size_t)node * 576;
  orow[lane] = acc[0];
#pragma unroll
  for (int t2 = 0; t2 < 3; t2++) orow[64 + 3*lane + t2] = acc[1 + t2];
#pragma unroll
  for (int t2 = 0; t2 < 5; t2++) orow[256 + 5*lane + t2] = acc[4 + t2];
}

// ============================================================
// Fallback (only if ws is too small for CSR): edge-parallel with atomics
// ============================================================
__global__ __launch_bounds__(256) void tp_edge_atomic(
    const float* __restrict__ x, const float* __restrict__ sh,
    const int* __restrict__ src, const int* __restrict__ dst,
    const float* __restrict__ Tg, float* __restrict__ out, int E)
{
  __shared__ float Tl[729];
  __shared__ __align__(16) float Wl[4][112];
  for (int i = threadIdx.x; i < 729; i += 256) Tl[i] = Tg[i];
  __syncthreads();

  const int wv = threadIdx.x >> 6;
  const int lane = threadIdx.x & 63;
  const int e = blockIdx.x * 4 + wv;
  if (e >= E) return;

  const int i0 = lane / 9, k0 = lane % 9;
  const bool has1 = (lane < 17);
  const int i1 = (lane + 64) / 9, k1 = (lane + 64) % 9;
  float* Wp = Wl[wv];

  const int sn = src[e];
  const float* she = sh + (size_t)e * 9;
  float sv[9];
#pragma unroll
  for (int j = 0; j < 9; j++) sv[j] = she[j];

  float w0 = 0.f;
#pragma unroll
  for (int j = 0; j < 9; j++) w0 += sv[j] * Tl[i0*81 + j*9 + k0];
  Wp[i0*12 + k0] = w0;
  if (has1){
    float w1 = 0.f;
#pragma unroll
    for (int j = 0; j < 9; j++) w1 += sv[j] * Tl[i1*81 + j*9 + k1];
    Wp[i1*12 + k1] = w1;
  }
  asm volatile("s_waitcnt lgkmcnt(0)" ::: "memory");

  const float* xr = x + (size_t)sn * 576;
  float xv[9];
  xv[0] = xr[lane];
#pragma unroll
  for (int t2 = 0; t2 < 3; t2++) xv[1 + t2] = xr[64 + 3*lane + t2];
#pragma unroll
  for (int t2 = 0; t2 < 5; t2++) xv[4 + t2] = xr[256 + 5*lane + t2];

  float o[9];
#pragma unroll
  for (int k = 0; k < 9; k++) o[k] = 0.f;
#pragma unroll
  for (int i = 0; i < 9; i++){
    const float4* wr4 = reinterpret_cast<const float4*>(Wp + i*12);
    float4 wa = wr4[0];
    float4 wb = wr4[1];
    float  w8 = Wp[i*12 + 8];
    float xi = xv[i];
    o[0] += xi * wa.x; o[1] += xi * wa.y; o[2] += xi * wa.z; o[3] += xi * wa.w;
    o[4] += xi * wb.x; o[5] += xi * wb.y; o[6] += xi * wb.z; o[7] += xi * wb.w;
    o[8] += xi * w8;
  }

  float* orow = out + (size_t)dst[e] * 576;
  atomicAdd(&orow[lane], o[0]);
#pragma unroll
  for (int t2 = 0; t2 < 3; t2++) atomicAdd(&orow[64 + 3*lane + t2], o[1 + t2]);
#pragma unroll
  for (int t2 = 0; t2 < 5; t2++) atomicAdd(&orow[256 + 5*lane + t2], o[4 + t2]);
}

// ============================================================
extern "C" void kernel_launch(void* const* d_in, const int* in_sizes, int n_in,
                              void* d_out, int out_size, void* d_ws, size_t ws_size,
                              hipStream_t stream)
{
  const float* x  = (const float*)d_in[0];
  const float* sh = (const float*)d_in[1];
  const int* src  = (const int*)d_in[2];
  const int* dst  = (const int*)d_in[3];
  float* out = (float*)d_out;

  const int N = in_sizes[0] / 576;
  const int E = in_sizes[2];

  float* Tw = (float*)d_ws;  // 729 floats (padded region: 1024)
  const size_t need = (size_t)(1024 + N + (N + 1) + E + E) * 4;

  gen_T_kernel<<<3, 256, 0, stream>>>(Tw);

  if (ws_size >= need){
    int* cnt  = (int*)d_ws + 1024;
    int* strt = cnt + N;
    int* pos  = strt + N + 1;
    int* csr  = pos + E;

    hipMemsetAsync(cnt, 0, (size_t)N * 4, stream);
    hist_kernel<<<(E + 255) / 256, 256, 0, stream>>>(dst, cnt, pos, E);
    scan_kernel<<<1, 1024, 0, stream>>>(cnt, strt, N);
    fill_kernel<<<(E + 255) / 256, 256, 0, stream>>>(dst, strt, pos, csr, E);
    tp_csr_kernel<<<(N + 3) / 4, 256, 0, stream>>>(x, sh, src, csr, strt, Tw, out, N);
  } else {
    hipMemsetAsync(out, 0, (size_t)out_size * 4, stream);
    tp_edge_atomic<<<(E + 3) / 4, 256, 0, stream>>>(x, sh, src, dst, Tw, out, E);
  }
}

// Round 3
// 182.631 us; speedup vs baseline: 1.0854x; 1.0854x over previous
//
#include <hip/hip_runtime.h>

// ============================================================
// Compile-time reproduction of np.random.RandomState(0).randn
// (MT19937 + polar Box-Muller). All control flow / uniforms are
// exact integer & IEEE-double arithmetic -> constexpr-safe.
// Only log/sqrt are evaluated on device (ulp-level differences
// are far below the validation threshold).
// ============================================================
struct MTS { unsigned int mt[624]; int mti; };

constexpr unsigned int mt_next(MTS& s){
  if (s.mti >= 624){
    for (int i = 0; i < 624; i++){
      unsigned int y = (s.mt[i] & 0x80000000u) | (s.mt[(i+1)%624] & 0x7fffffffu);
      unsigned int v = s.mt[(i+397)%624] ^ (y >> 1);
      if (y & 1u) v ^= 2567483615u;   // 0x9908b0df
      s.mt[i] = v;
    }
    s.mti = 0;
  }
  unsigned int y = s.mt[s.mti]; s.mti++;
  y ^= y >> 11;
  y ^= (y << 7)  & 2636928640u;  // 0x9d2c5680
  y ^= (y << 15) & 4022730752u;  // 0xefc60000
  y ^= y >> 18;
  return y;
}
constexpr double mt_dbl(MTS& s){
  unsigned int a = mt_next(s) >> 5;
  unsigned int b = mt_next(s) >> 6;
  return ((double)a * 67108864.0 + (double)b) / 9007199254740992.0;
}

constexpr int NPAIR = 308;   // 615 gaussians -> 308 polar pairs
struct GenData {
  double r2[NPAIR], x1[NPAIR], x2[NPAIR];
  int g_of_t[729];           // T flat index -> gauss index (-1 = structural zero)
};

constexpr GenData make_gen(){
  GenData g{};
  for (int i = 0; i < 729; i++) g.g_of_t[i] = -1;
  MTS s{};
  {
    unsigned int sd = 0u;    // RandomState(0)
    for (int p = 0; p < 624; p++){
      s.mt[p] = sd;
      sd = 1812433253u * (sd ^ (sd >> 30)) + (unsigned)p + 1u;
    }
    s.mti = 624;
  }
  for (int p = 0; p < NPAIR; p++){
    double a = 0.0, b = 0.0, r = 0.0;
    do {
      a = 2.0 * mt_dbl(s) - 1.0;
      b = 2.0 * mt_dbl(s) - 1.0;
      r = a*a + b*b;
    } while (r >= 1.0 || r == 0.0);
    g.r2[p] = r; g.x1[p] = a; g.x2[p] = b;
  }
  // PATHS in module order; OFF = {0,1,4}
  const int L1[15] = {0,0,0,1,1,1,1,1,1,2,2,2,2,2,2};
  const int L2[15] = {0,1,2,0,1,1,1,2,2,0,1,1,2,2,2};
  const int L3[15] = {0,1,2,1,0,1,2,1,2,2,1,2,0,1,2};
  const int OFF[3] = {0,1,4};
  int gi = 0;
  for (int p = 0; p < 15; p++){
    int d1 = 2*L1[p]+1, d2 = 2*L2[p]+1, d3 = 2*L3[p]+1;
    for (int i = 0; i < d1; i++)
      for (int j = 0; j < d2; j++)
        for (int k = 0; k < d3; k++)
          g.g_of_t[(OFF[L1[p]]+i)*81 + (OFF[L2[p]]+j)*9 + (OFF[L3[p]]+k)] = gi++;
  }
  return g;
}

constexpr GenData h_gd = make_gen();
__constant__ GenData c_gd = h_gd;

// Writes the dense 9x9x9 tensor T (615 CG values + zeros) to ws.
__global__ void gen_T_kernel(float* __restrict__ T){
  int t = blockIdx.x * blockDim.x + threadIdx.x;
  if (t >= 729) return;
  int gi = c_gd.g_of_t[t];
  float v = 0.f;
  if (gi >= 0){
    int p = gi >> 1;
    double r2 = c_gd.r2[p];
    double f  = sqrt(-2.0 * log(r2) / r2);
    double xx = (gi & 1) ? c_gd.x1[p] : c_gd.x2[p];
    v = (float)((f * xx) / 3.0);
  }
  T[t] = v;
}

// ============================================================
// CSR-by-dst construction: hist -> scan -> fill (+ reorder src & sh)
// ============================================================
__global__ __launch_bounds__(256) void hist_kernel(const int* __restrict__ dst,
                                                   int* __restrict__ cnt,
                                                   int* __restrict__ pos, int E){
  int e = blockIdx.x * 256 + threadIdx.x;
  if (e < E) pos[e] = atomicAdd(&cnt[dst[e]], 1);
}

__global__ void scan_kernel(const int* __restrict__ cnt, int* __restrict__ start, int n){
  __shared__ int part[1024];
  int t = threadIdx.x;
  int ch = (n + 1023) >> 10;
  int b0 = t * ch;
  int sum = 0;
  for (int j = 0; j < ch; j++){ int i = b0 + j; if (i < n) sum += cnt[i]; }
  part[t] = sum;
  __syncthreads();
  for (int off = 1; off < 1024; off <<= 1){
    int v = 0;
    if (t >= off) v = part[t - off];
    __syncthreads();
    part[t] += v;
    __syncthreads();
  }
  int run = (t > 0) ? part[t-1] : 0;
  for (int j = 0; j < ch; j++){
    int i = b0 + j;
    if (i < n){ start[i] = run; run += cnt[i]; }
  }
  if (t == 1023) start[n] = part[1023];
}

// Writes src and sh reordered into CSR-by-dst order: the tp kernel then
// reads everything with LINEAR indices (no indirection chain).
__global__ __launch_bounds__(256) void fill_kernel(const int* __restrict__ dst,
                                                   const int* __restrict__ src,
                                                   const float* __restrict__ sh,
                                                   const int* __restrict__ start,
                                                   const int* __restrict__ pos,
                                                   int* __restrict__ esrc,
                                                   float* __restrict__ sh_r, int E){
  int e = blockIdx.x * 256 + threadIdx.x;
  if (e >= E) return;
  int p = start[dst[e]] + pos[e];
  esrc[p] = src[e];
  const float* s9 = sh + (size_t)e * 9;
  float* d9 = sh_r + (size_t)p * 9;
#pragma unroll
  for (int j = 0; j < 9; j++) d9[j] = s9[j];
}

// ============================================================
// Main TP kernel: one wave per node, lane = channel (64). NO LDS.
// Per edge:
//   - x-row loads issued first (latency hides under W build)
//   - W[i][k] = sum_j sh[j]*T[i][j][k]: T held in per-lane REGISTERS
//     (constant across edges); lane l computes W[l] (and l<17: W[64+l])
//   - matvec reads W via v_readlane (compile-time lane) -> SGPR
//     broadcast operand of v_fmac_f32. No LDS, no barriers.
// ============================================================
__device__ __forceinline__ float bcast_lane(float v, int lane){
  return __uint_as_float(__builtin_amdgcn_readlane(__float_as_uint(v), lane));
}

__global__ __launch_bounds__(256) void tp_csr_kernel(
    const float* __restrict__ x, const float* __restrict__ sh_r,
    const int* __restrict__ esrc, const int* __restrict__ starts,
    const float* __restrict__ Tg, float* __restrict__ out, int n_nodes)
{
  const int wv = threadIdx.x >> 6;
  const int lane = threadIdx.x & 63;
  const int node = blockIdx.x * 4 + wv;
  if (node >= n_nodes) return;

  // per-lane constant T fragments (entry t = i*9+k; lane owns t=lane and t=64+lane)
  const int i0 = lane / 9, k0 = lane % 9;
  const bool has1 = (lane < 17);
  const int e1 = has1 ? (64 + lane) : 63;     // clamp to stay in-bounds
  const int i1 = e1 / 9, k1 = e1 % 9;
  float t0[9], t1[9];
#pragma unroll
  for (int j = 0; j < 9; j++){
    t0[j] = Tg[i0*81 + j*9 + k0];
    t1[j] = Tg[i1*81 + j*9 + k1];
  }

  float acc[9];
#pragma unroll
  for (int k = 0; k < 9; k++) acc[k] = 0.f;

  const int s0 = starts[node];
  const int s1 = starts[node + 1];

  if (s0 < s1){
    // prologue: load first edge's sn + sh
    int sn_c = esrc[s0];
    float sh_c[9];
    {
      const float* p9 = sh_r + (size_t)s0 * 9;
#pragma unroll
      for (int j = 0; j < 9; j++) sh_c[j] = p9[j];
    }

    for (int idx = s0; idx < s1; ++idx){
      // ---- issue x-row loads for current edge (latency hides under W build)
      const float* xr = x + (size_t)sn_c * 576;
      float xv[9];
      xv[0] = xr[lane];
#pragma unroll
      for (int t = 0; t < 3; t++) xv[1 + t] = xr[64 + 3*lane + t];
#pragma unroll
      for (int t = 0; t < 5; t++) xv[4 + t] = xr[256 + 5*lane + t];

      // ---- prefetch next edge's sn + sh
      const int nidx = (idx + 1 < s1) ? (idx + 1) : idx;
      const int sn_n = esrc[nidx];
      float sh_n[9];
      {
        const float* p9 = sh_r + (size_t)nidx * 9;
#pragma unroll
        for (int j = 0; j < 9; j++) sh_n[j] = p9[j];
      }

      // ---- cooperative W build, all in registers
      float w0 = 0.f, w1 = 0.f;
#pragma unroll
      for (int j = 0; j < 9; j++) w0 = fmaf(sh_c[j], t0[j], w0);
#pragma unroll
      for (int j = 0; j < 9; j++) w1 = fmaf(sh_c[j], t1[j], w1);

      // ---- matvec: acc[k] += xv[i] * W[i*9+k]; W via readlane broadcast
#pragma unroll
      for (int i = 0; i < 9; i++){
        const float xi = xv[i];
#pragma unroll
        for (int k = 0; k < 9; k++){
          const int t = i*9 + k;
          const float w = (t < 64) ? bcast_lane(w0, t) : bcast_lane(w1, t - 64);
          acc[k] = fmaf(xi, w, acc[k]);
        }
      }

      sn_c = sn_n;
#pragma unroll
      for (int j = 0; j < 9; j++) sh_c[j] = sh_n[j];
    }
  }

  float* orow = out + (size_t)node * 576;
  orow[lane] = acc[0];
#pragma unroll
  for (int t = 0; t < 3; t++) orow[64 + 3*lane + t] = acc[1 + t];
#pragma unroll
  for (int t = 0; t < 5; t++) orow[256 + 5*lane + t] = acc[4 + t];
}

// ============================================================
// Fallback (only if ws is too small for CSR): edge-parallel with atomics
// ============================================================
__global__ __launch_bounds__(256) void tp_edge_atomic(
    const float* __restrict__ x, const float* __restrict__ sh,
    const int* __restrict__ src, const int* __restrict__ dst,
    const float* __restrict__ Tg, float* __restrict__ out, int E)
{
  const int wv = threadIdx.x >> 6;
  const int lane = threadIdx.x & 63;
  const int e = blockIdx.x * 4 + wv;
  if (e >= E) return;

  const int i0 = lane / 9, k0 = lane % 9;
  const bool has1 = (lane < 17);
  const int e1 = has1 ? (64 + lane) : 63;
  const int i1 = e1 / 9, k1 = e1 % 9;
  float t0[9], t1[9];
#pragma unroll
  for (int j = 0; j < 9; j++){
    t0[j] = Tg[i0*81 + j*9 + k0];
    t1[j] = Tg[i1*81 + j*9 + k1];
  }

  const int sn = src[e];
  const float* she = sh + (size_t)e * 9;
  float sv[9];
#pragma unroll
  for (int j = 0; j < 9; j++) sv[j] = she[j];

  float w0 = 0.f, w1 = 0.f;
#pragma unroll
  for (int j = 0; j < 9; j++) w0 = fmaf(sv[j], t0[j], w0);
#pragma unroll
  for (int j = 0; j < 9; j++) w1 = fmaf(sv[j], t1[j], w1);

  const float* xr = x + (size_t)sn * 576;
  float xv[9];
  xv[0] = xr[lane];
#pragma unroll
  for (int t = 0; t < 3; t++) xv[1 + t] = xr[64 + 3*lane + t];
#pragma unroll
  for (int t = 0; t < 5; t++) xv[4 + t] = xr[256 + 5*lane + t];

  float o[9];
#pragma unroll
  for (int k = 0; k < 9; k++) o[k] = 0.f;
#pragma unroll
  for (int i = 0; i < 9; i++){
    const float xi = xv[i];
#pragma unroll
    for (int k = 0; k < 9; k++){
      const int t = i*9 + k;
      const float w = (t < 64) ? bcast_lane(w0, t) : bcast_lane(w1, t - 64);
      o[k] = fmaf(xi, w, o[k]);
    }
  }

  float* orow = out + (size_t)dst[e] * 576;
  atomicAdd(&orow[lane], o[0]);
#pragma unroll
  for (int t = 0; t < 3; t++) atomicAdd(&orow[64 + 3*lane + t], o[1 + t]);
#pragma unroll
  for (int t = 0; t < 5; t++) atomicAdd(&orow[256 + 5*lane + t], o[4 + t]);
}

// ============================================================
extern "C" void kernel_launch(void* const* d_in, const int* in_sizes, int n_in,
                              void* d_out, int out_size, void* d_ws, size_t ws_size,
                              hipStream_t stream)
{
  const float* x  = (const float*)d_in[0];
  const float* sh = (const float*)d_in[1];
  const int* src  = (const int*)d_in[2];
  const int* dst  = (const int*)d_in[3];
  float* out = (float*)d_out;

  const int N = in_sizes[0] / 576;
  const int E = in_sizes[2];

  float* Tw = (float*)d_ws;  // 729 floats (padded region: 1024)
  // layout: Tw[1024] | cnt[N] | strt[N+1] | pos[E] | esrc[E] | sh_r[9E]
  const size_t need = ((size_t)1024 + N + (N + 1) + E + E + (size_t)9 * E) * 4;

  gen_T_kernel<<<3, 256, 0, stream>>>(Tw);

  if (ws_size >= need){
    int* cnt    = (int*)d_ws + 1024;
    int* strt   = cnt + N;
    int* pos    = strt + N + 1;
    int* esrc   = pos + E;
    float* sh_r = (float*)(esrc + E);

    hipMemsetAsync(cnt, 0, (size_t)N * 4, stream);
    hist_kernel<<<(E + 255) / 256, 256, 0, stream>>>(dst, cnt, pos, E);
    scan_kernel<<<1, 1024, 0, stream>>>(cnt, strt, N);
    fill_kernel<<<(E + 255) / 256, 256, 0, stream>>>(dst, src, sh, strt, pos, esrc, sh_r, E);
    tp_csr_kernel<<<(N + 3) / 4, 256, 0, stream>>>(x, sh_r, esrc, strt, Tw, out, N);
  } else {
    hipMemsetAsync(out, 0, (size_t)out_size * 4, stream);
    tp_edge_atomic<<<(E + 3) / 4, 256, 0, stream>>>(x, sh, src, dst, Tw, out, E);
  }
}